// Round 1
// baseline (86.634 us; speedup 1.0000x reference)
//
#include <hip/hip_runtime.h>

#define T_LEN 256
#define NG 25              // 25 groups x 16 steps = 400 steps (need s_max = 398)

__device__ __forceinline__ float ex2(float x) { return __builtin_amdgcn_exp2f(x); }
__device__ __forceinline__ float rcpf_(float x) { return __builtin_amdgcn_rcpf(x); }

// Shift-with-fill: lane i <- lane i-1 (wave_shr:1, 0x138); lane 0 (sourceless,
// bound_ctrl=false) keeps OLD = fill. One instruction on the chain.
__device__ __forceinline__ float dpp_shr1_fill(float fill, float v) {
    int f = __float_as_int(fill), i = __float_as_int(v);
    return __int_as_float(__builtin_amdgcn_update_dpp(f, i, 0x138, 0xF, 0xF, false));
}
// Shift-with-fill the other way: lane i <- lane i+1 (wave_shl:1, 0x130);
// lane 63 (sourceless) keeps OLD = fill. Fuses the conveyor rotate+inject.
__device__ __forceinline__ float dpp_shl1_fill(float fill, float v) {
    int f = __float_as_int(fill), i = __float_as_int(v);
    return __int_as_float(__builtin_amdgcn_update_dpp(f, i, 0x130, 0xF, 0xF, false));
}

// LDS-only barrier. __syncthreads() lowers to s_waitcnt vmcnt(0) lgkmcnt(0) +
// s_barrier: the vmcnt(0) drain serializes the fire-and-forget global out
// stores (~500+cy each, 4 groups) into the step loop. Ring/sx ordering only
// needs lgkmcnt. "memory" clobber keeps the ds_write dump above the wait.
__device__ __forceinline__ void barrier_lds() {
    asm volatile("s_waitcnt lgkmcnt(0)" ::: "memory");
    __builtin_amdgcn_s_barrier();
}

// R19: R18 skeleton + three scheduling/chain changes (step count, store
// schedule, seam/races unchanged — R16/R18 proofs carry over):
//  (1) den-fold: den = (1+En)(1+Ez) = fma(En, az, az), az = 1+Ez OFF-chain.
//      Removes the t1-add from the En->den->rcp->mul critical path. num keeps
//      the old (t1, bb) form; t1/bb/num complete under the den-fma+rcp shadow.
//      Freeze path bit-identical: Ez:=0 -> az=1 -> den = fma(En,1,1) = 1+En.
//  (2) pk software pipeline, zero extra steps:
//      - wave1: pk[0] for group g lives at slot (16g-17)&63, dumped at end of
//        group g-2 -> read it one barrier EARLY into pk0n (register carry).
//        Fresh reads k=1..15 have >=1 step (~200cy) of slack >= ds_read
//        latency (~120cy) -> the per-group ~120cy lgkm stall on pk[0] is gone.
//      - wave0: sx is constant -> full one-group-ahead prefetch into pkn.
//  (3) barrier_lds() instead of __syncthreads() (see above).
// TWO waves, 1 layer/lane. cell (l,t) at step s = t + l + 16*(l>=64).
//  - step-head input: in = dpp(old=pk[k], src=h, wave_shr:1)  (R17).
//  - output conveyor fused: ov = dpp(old=h, src=ov, wave_shl:1) (R18).
//  - ramp loop g=0..8 (freeze), steady loop g=9..24 (freeze-free) (R18).
//  - seam ring: per-GROUP conveyor dump; reads barrier-covered, races
//    disjoint-or-identical, overwrite >=2 barriers away (R16 proof; pk0n's
//    early read targets a slot written 2 dumps ago, overwritten 3 dumps
//    later -> same argument).
//  - out: coalesced 64-lane stores at s=206,270,334,398 (k==14, g=12,16,20,24).
__global__ __launch_bounds__(128, 1) void gru_stack_wavefront(
    const float* __restrict__ x,
    const float* __restrict__ w_ih,
    const float* __restrict__ w_hh,
    const float* __restrict__ b_ih,
    const float* __restrict__ b_hh,
    float* __restrict__ out)
{
    __shared__ float ring[2 * 64];        // [wid][slot]: h(63) / h(127) history
    __shared__ float sx[T_LEN];
    const int tid  = threadIdx.x;         // 0..127 == layer index
    const int lane = tid & 63;
    const int wid  = tid >> 6;

    ring[tid] = 0.0f;                     // zero-init both planes
    sx[tid] = x[tid];
    sx[tid + 128] = x[tid + 128];

    const float L1 = -1.4426950408889634f;   // -log2(e)
    const float L2 = -2.8853900817779268f;   // -2*log2(e)

    const float wi_r = L1 * w_ih[3 * tid + 0], wh_r = L1 * w_hh[3 * tid + 0];
    const float b_r  = L1 * (b_ih[3 * tid + 0] + b_hh[3 * tid + 0]);
    const float wi_z = L1 * w_ih[3 * tid + 1], wh_z = L1 * w_hh[3 * tid + 1];
    const float b_z  = L1 * (b_ih[3 * tid + 1] + b_hh[3 * tid + 1]);
    const float wi_n = L2 * w_ih[3 * tid + 2], bi_n = L2 * b_ih[3 * tid + 2];
    const float wh_n = L2 * w_hh[3 * tid + 2], bh_n = L2 * b_hh[3 * tid + 2];

    float h = 0.0f;
    float c_r = b_r, c_z = b_z, g_n = bh_n;

    float pk[16];                         // current group's fill values
    float pkn[16];                        // wave0: next group's sx (prefetch)
    #pragma unroll
    for (int k = 0; k < 16; ++k) { pk[k] = 0.0f; pkn[k] = 0.0f; }
    float pk0n = 0.0f;                    // wave1: next group's pk[0] (carry)

    float ov = 0.0f;                      // conveyor: w0 feeds seam dump, w1 out
    int t = -lane - 80 * wid - 1;         // ++ at step top (ramp loop only)

    const bool is_w1 = (wid == 1);
    float* ringw = &ring[wid * 64];       // own plane (w1's never read)

    barrier_lds();                        // ring + sx init visible

    if (!is_w1) {
        #pragma unroll
        for (int k = 0; k < 16; ++k) pk[k] = sx[k];      // group 0 inputs
    }
    // wave1 group-0 pk stays 0 (slots (-17..-2)&63 are zero-init anyway)

    // ---------- ramp loop: g = 0..8 (s = 0..143), freeze active ----------
    for (int g = 0; g < 9; ++g) {
        if (is_w1) {
            const int base = 16 * g - 17;
            #pragma unroll
            for (int k = 1; k < 16; ++k)
                pk[k] = ring[(base + k) & 63];           // fresh (dumped @ g-1)
            pk0n = ring[(base + 16) & 63];               // next group's k=0
        } else {
            const int b2 = 16 * g + 16;                  // b2+15 <= 159 < 256
            #pragma unroll
            for (int k = 0; k < 16; ++k)
                pkn[k] = sx[b2 + k];                     // next group's x
        }

        #pragma unroll
        for (int k = 0; k < 16; ++k) {
            ++t;
            const bool valid = (unsigned)t < (unsigned)T_LEN;

            float in = dpp_shr1_fill(pk[k], h);          // one-instr input path

            float u_r  = fmaf(wi_r, in, c_r);
            float u_z  = fmaf(wi_z, in, c_z);
            float u_n0 = fmaf(wi_n, in, bi_n);
            float r  = rcpf_(1.0f + ex2(u_r));
            float Ez = ex2(u_z);
            Ez = valid ? Ez : 0.0f;                      // freeze: h' = h (exact at h=0)
            float az  = 1.0f + Ez;                       // off-chain
            float En = ex2(fmaf(r, g_n, u_n0));
            float t1  = 1.0f + En;                       // off-chain now
            float den = fmaf(En, az, az);                // (1+En)(1+Ez), chain
            float bb  = fmaf(-Ez, En, Ez);               // E_z(1-E_n), off-chain
            float num = fmaf(h, t1, bb);                 // h(1+E_n) + E_z(1-E_n)
            h = num * rcpf_(den);

            c_r = fmaf(wh_r, h, b_r);
            c_z = fmaf(wh_z, h, b_z);
            g_n = fmaf(wh_n, h, bh_n);

            ov = dpp_shl1_fill(h, ov);                   // fused rotate+inject
        }
        ringw[(16 * g + 16 + lane) & 63] = ov;           // group-end dump
        if (is_w1) {
            pk[0] = pk0n;                                // register carry
        } else {
            #pragma unroll
            for (int k = 0; k < 16; ++k) pk[k] = pkn[k]; // promote prefetch
        }
        barrier_lds();
    }

    // ---------- steady loop: g = 9..24, freeze-free (ramp-out garbage
    // provably never consumed; NaN contained — see R18 header) ----------
    for (int g = 9; g < NG; ++g) {
        if (is_w1) {
            const int base = 16 * g - 17;
            #pragma unroll
            for (int k = 1; k < 16; ++k)
                pk[k] = ring[(base + k) & 63];           // fresh (dumped @ g-1)
            pk0n = ring[(base + 16) & 63];               // next group's k=0
        } else {
            const int b2 = 16 * g + 16;
            #pragma unroll
            for (int k = 0; k < 16; ++k)
                pkn[k] = sx[(b2 + k) & (T_LEN - 1)];     // wrap: dead lanes only
        }

        #pragma unroll
        for (int k = 0; k < 16; ++k) {
            float in = dpp_shr1_fill(pk[k], h);          // one-instr input path

            float u_r  = fmaf(wi_r, in, c_r);
            float u_z  = fmaf(wi_z, in, c_z);
            float u_n0 = fmaf(wi_n, in, bi_n);
            float r  = rcpf_(1.0f + ex2(u_r));
            float Ez = ex2(u_z);
            float az  = 1.0f + Ez;                       // off-chain
            float En = ex2(fmaf(r, g_n, u_n0));
            float t1  = 1.0f + En;                       // off-chain
            float den = fmaf(En, az, az);                // (1+En)(1+Ez), chain
            float bb  = fmaf(-Ez, En, Ez);               // off-chain
            float num = fmaf(h, t1, bb);                 // under den->rcp shadow
            h = num * rcpf_(den);

            c_r = fmaf(wh_r, h, b_r);
            c_z = fmaf(wh_z, h, b_z);
            g_n = fmaf(wh_n, h, bh_n);

            ov = dpp_shl1_fill(h, ov);                   // fused rotate+inject

            if (k == 14) {                               // s = 206,270,334,398
                if (is_w1 && (g & 3) == 0 && g >= 12)
                    out[16 * g - 192 + lane] = ov;       // coalesced store
            }
        }
        ringw[(16 * g + 16 + lane) & 63] = ov;           // group-end dump
        if (is_w1) {
            pk[0] = pk0n;                                // register carry
        } else {
            #pragma unroll
            for (int k = 0; k < 16; ++k) pk[k] = pkn[k]; // promote prefetch
        }
        barrier_lds();
    }
}

extern "C" void kernel_launch(void* const* d_in, const int* in_sizes, int n_in,
                              void* d_out, int out_size, void* d_ws, size_t ws_size,
                              hipStream_t stream) {
    const float* x    = (const float*)d_in[0];  // [1,256]
    const float* w_ih = (const float*)d_in[1];  // [128,3,1]
    const float* w_hh = (const float*)d_in[2];  // [128,3,1]
    const float* b_ih = (const float*)d_in[3];  // [128,3]
    const float* b_hh = (const float*)d_in[4];  // [128,3]
    float* out = (float*)d_out;                 // [1,256]

    gru_stack_wavefront<<<1, 128, 0, stream>>>(x, w_ih, w_hh, b_ih, b_hh, out);
}

// Round 2
// 85.384 us; speedup vs baseline: 1.0146x; 1.0146x over previous
//
#include <hip/hip_runtime.h>

#define T_LEN 256
#define NG 25              // 25 groups x 16 steps = 400 steps (need s_max = 398)

__device__ __forceinline__ float ex2(float x) { return __builtin_amdgcn_exp2f(x); }
__device__ __forceinline__ float rcpf_(float x) { return __builtin_amdgcn_rcpf(x); }

// Shift-with-fill: lane i <- lane i-1 (wave_shr:1, 0x138); lane 0 (sourceless,
// bound_ctrl=false) keeps OLD = fill. One instruction on the chain.
__device__ __forceinline__ float dpp_shr1_fill(float fill, float v) {
    int f = __float_as_int(fill), i = __float_as_int(v);
    return __int_as_float(__builtin_amdgcn_update_dpp(f, i, 0x138, 0xF, 0xF, false));
}
// Shift-with-fill the other way: lane i <- lane i+1 (wave_shl:1, 0x130);
// lane 63 (sourceless) keeps OLD = fill. Fuses the conveyor rotate+inject.
__device__ __forceinline__ float dpp_shl1_fill(float fill, float v) {
    int f = __float_as_int(fill), i = __float_as_int(v);
    return __int_as_float(__builtin_amdgcn_update_dpp(f, i, 0x130, 0xF, 0xF, false));
}

// R20 = R18 skeleton (the proven 83.5us kernel, byte-for-byte) + ONE change:
//   den-fold: den = (1+En)(1+Ez) = fma(En, az, az) with az = 1+Ez OFF-chain
//   (Ez is ready ~2 trans-latencies before En). Old chain after En was
//   t1-add -> den-fma -> rcp -> mul; new chain is den-fma -> rcp -> mul.
//   t1 = 1+En is still computed (num needs it) but now sits under the
//   den-fma + rcp shadow, off the h->h' critical path. -1 dependent op/step.
//   Freeze path bit-identical: Ez := 0 -> az = 1 -> den = fma(En,1,1) = 1+En,
//   bb = 0, num = h*t1 -> h' = h*t1*rcp(t1), exactly as R18 (h==0 stays 0).
// Everything else unchanged from R18 (R1's bundled sched changes REVERTED:
// plain __syncthreads(), all-16 fresh pk reads, no prefetch registers).
// TWO waves, 1 layer/lane. cell (l,t) at step s = t + l + 16*(l>=64).
//  - step-head input: in = dpp(old=pk[k], src=h, wave_shr:1)  (R17).
//  - output conveyor fused: ov = dpp(old=h, src=ov, wave_shl:1) (R18).
//  - ramp loop g=0..8 (freeze), steady loop g=9..24 (freeze-free) (R18).
//  - seam ring: per-GROUP conveyor dump; reads barrier-covered, races
//    disjoint-or-identical, overwrite >=2 barriers away (R16 proof).
//  - out: coalesced 64-lane stores at s=206,270,334,398 (k==14, g=12,16,20,24).
__global__ __launch_bounds__(128, 1) void gru_stack_wavefront(
    const float* __restrict__ x,
    const float* __restrict__ w_ih,
    const float* __restrict__ w_hh,
    const float* __restrict__ b_ih,
    const float* __restrict__ b_hh,
    float* __restrict__ out)
{
    __shared__ float ring[2 * 64];        // [wid][slot]: h(63) / h(127) history
    __shared__ float sx[T_LEN];
    const int tid  = threadIdx.x;         // 0..127 == layer index
    const int lane = tid & 63;
    const int wid  = tid >> 6;

    ring[tid] = 0.0f;                     // zero-init both planes
    sx[tid] = x[tid];
    sx[tid + 128] = x[tid + 128];

    const float L1 = -1.4426950408889634f;   // -log2(e)
    const float L2 = -2.8853900817779268f;   // -2*log2(e)

    const float wi_r = L1 * w_ih[3 * tid + 0], wh_r = L1 * w_hh[3 * tid + 0];
    const float b_r  = L1 * (b_ih[3 * tid + 0] + b_hh[3 * tid + 0]);
    const float wi_z = L1 * w_ih[3 * tid + 1], wh_z = L1 * w_hh[3 * tid + 1];
    const float b_z  = L1 * (b_ih[3 * tid + 1] + b_hh[3 * tid + 1]);
    const float wi_n = L2 * w_ih[3 * tid + 2], bi_n = L2 * b_ih[3 * tid + 2];
    const float wh_n = L2 * w_hh[3 * tid + 2], bh_n = L2 * b_hh[3 * tid + 2];

    float h = 0.0f;
    float c_r = b_r, c_z = b_z, g_n = bh_n;

    float pk[16];
    #pragma unroll
    for (int k = 0; k < 16; ++k) pk[k] = 0.0f;

    float ov = 0.0f;                      // conveyor: w0 feeds seam dump, w1 out
    int t = -lane - 80 * wid - 1;         // ++ at step top (ramp loop only)

    const bool is_w1 = (wid == 1);
    float* ringw = &ring[wid * 64];       // own plane (w1's never read)

    __syncthreads();                      // ring + sx init visible

    // ---------- ramp loop: g = 0..8 (s = 0..143), freeze active ----------
    for (int g = 0; g < 9; ++g) {
        if (is_w1) {
            const int base = 16 * g - 17;
            #pragma unroll
            for (int k = 0; k < 16; ++k)
                pk[k] = ring[(base + k) & 63];           // h(63, s-17)
        } else {
            #pragma unroll
            for (int k = 0; k < 16; ++k)
                pk[k] = sx[16 * g + k];                  // x[s], s <= 143
        }

        #pragma unroll
        for (int k = 0; k < 16; ++k) {
            ++t;
            const bool valid = (unsigned)t < (unsigned)T_LEN;

            float in = dpp_shr1_fill(pk[k], h);          // one-instr input path

            float u_r  = fmaf(wi_r, in, c_r);
            float u_z  = fmaf(wi_z, in, c_z);
            float u_n0 = fmaf(wi_n, in, bi_n);
            float r  = rcpf_(1.0f + ex2(u_r));
            float Ez = ex2(u_z);
            Ez = valid ? Ez : 0.0f;                      // freeze: h' = h (exact at h=0)
            float az  = 1.0f + Ez;                       // off-chain (Ez ready early)
            float En = ex2(fmaf(r, g_n, u_n0));
            float t1  = 1.0f + En;                       // off-chain now
            float den = fmaf(En, az, az);                // (1+E_n)(1+E_z), chain
            float bb  = fmaf(-Ez, En, Ez);               // E_z(1-E_n), off-chain
            float num = fmaf(h, t1, bb);                 // h(1+E_n) + E_z(1-E_n)
            h = num * rcpf_(den);

            c_r = fmaf(wh_r, h, b_r);
            c_z = fmaf(wh_z, h, b_z);
            g_n = fmaf(wh_n, h, bh_n);

            ov = dpp_shl1_fill(h, ov);                   // fused rotate+inject
        }
        ringw[(16 * g + 16 + lane) & 63] = ov;           // group-end dump
        __syncthreads();
    }

    // ---------- steady loop: g = 9..24, freeze-free (ramp-out garbage
    // provably never consumed; NaN contained — see header) ----------
    for (int g = 9; g < NG; ++g) {
        if (is_w1) {
            const int base = 16 * g - 17;
            #pragma unroll
            for (int k = 0; k < 16; ++k)
                pk[k] = ring[(base + k) & 63];           // h(63, s-17)
        } else {
            #pragma unroll
            for (int k = 0; k < 16; ++k)
                pk[k] = sx[(16 * g + k) & (T_LEN - 1)];  // x[s] (wrap: dead lanes)
        }

        #pragma unroll
        for (int k = 0; k < 16; ++k) {
            float in = dpp_shr1_fill(pk[k], h);          // one-instr input path

            float u_r  = fmaf(wi_r, in, c_r);
            float u_z  = fmaf(wi_z, in, c_z);
            float u_n0 = fmaf(wi_n, in, bi_n);
            float r  = rcpf_(1.0f + ex2(u_r));
            float Ez = ex2(u_z);
            float az  = 1.0f + Ez;                       // off-chain
            float En = ex2(fmaf(r, g_n, u_n0));
            float t1  = 1.0f + En;                       // off-chain
            float den = fmaf(En, az, az);                // (1+E_n)(1+E_z), chain
            float bb  = fmaf(-Ez, En, Ez);               // off-chain
            float num = fmaf(h, t1, bb);                 // under den->rcp shadow
            h = num * rcpf_(den);

            c_r = fmaf(wh_r, h, b_r);
            c_z = fmaf(wh_z, h, b_z);
            g_n = fmaf(wh_n, h, bh_n);

            ov = dpp_shl1_fill(h, ov);                   // fused rotate+inject

            if (k == 14) {                               // s = 206,270,334,398
                if (is_w1 && (g & 3) == 0 && g >= 12)
                    out[16 * g - 192 + lane] = ov;       // coalesced store
            }
        }
        ringw[(16 * g + 16 + lane) & 63] = ov;           // group-end dump
        __syncthreads();
    }
}

extern "C" void kernel_launch(void* const* d_in, const int* in_sizes, int n_in,
                              void* d_out, int out_size, void* d_ws, size_t ws_size,
                              hipStream_t stream) {
    const float* x    = (const float*)d_in[0];  // [1,256]
    const float* w_ih = (const float*)d_in[1];  // [128,3,1]
    const float* w_hh = (const float*)d_in[2];  // [128,3,1]
    const float* b_ih = (const float*)d_in[3];  // [128,3]
    const float* b_hh = (const float*)d_in[4];  // [128,3]
    float* out = (float*)d_out;                 // [1,256]

    gru_stack_wavefront<<<1, 128, 0, stream>>>(x, w_ih, w_hh, b_ih, b_hh, out);
}

// Round 3
// 84.430 us; speedup vs baseline: 1.0261x; 1.0113x over previous
//
#include <hip/hip_runtime.h>

#define T_LEN 256
#define NG 25              // 25 groups x 16 steps = 400 steps (need s_max = 398)

__device__ __forceinline__ float ex2(float x) { return __builtin_amdgcn_exp2f(x); }
__device__ __forceinline__ float rcpf_(float x) { return __builtin_amdgcn_rcpf(x); }

// Shift-with-fill: lane i <- lane i-1 (wave_shr:1, 0x138); lane 0 (sourceless,
// bound_ctrl=false) keeps OLD = fill. One instruction on the chain.
__device__ __forceinline__ float dpp_shr1_fill(float fill, float v) {
    int f = __float_as_int(fill), i = __float_as_int(v);
    return __int_as_float(__builtin_amdgcn_update_dpp(f, i, 0x138, 0xF, 0xF, false));
}
// Shift-with-fill the other way: lane i <- lane i+1 (wave_shl:1, 0x130);
// lane 63 (sourceless) keeps OLD = fill. Fuses the conveyor rotate+inject.
__device__ __forceinline__ float dpp_shl1_fill(float fill, float v) {
    int f = __float_as_int(fill), i = __float_as_int(v);
    return __int_as_float(__builtin_amdgcn_update_dpp(f, i, 0x130, 0xF, 0xF, false));
}

// R21 = exact restore of the proven 83.48us kernel (R18 skeleton, round-0
// source, byte-identical). R19 (sched bundle) and R20 (den-fold) both
// regressed (+3.2us / +1.9us): the 16x-unrolled steady body sits in a
// fragile compiler-schedule optimum; source-level chain shortening loses
// more to schedule/regalloc perturbation than it saves in dependent ops.
//   z = 1/(1+E_z), n = (1-E_n)/(1+E_n)  (E_z = exp2(u_z'), E_n = exp2(un'))
//   h' = (1-z)n + zh = [E_z(1-E_n) + h(1+E_n)] / [(1+E_n)(1+E_z)]
// -> ONE rcp (of the product) replaces the two tail rcps: 5 transcendentals
// per step instead of 6; -1 add; +1 mul. Freeze ports exactly as E_z := 0
// (=> num = h*t1, den = t1, h' = h*t1*rcp(t1); ramp-in h==0 stays 0 EXACTLY).
// Ramp-out inf/NaN in dead lanes is contained: valid consumers only read
// valid-produced values (R18 proof); ring/conveyor garbage feeds only
// invalid cells whose outputs are never consumed.
// TWO waves, 1 layer/lane. cell (l,t) at step s = t + l + 16*(l>=64).
//  - step-head input: in = dpp(old=pk[k], src=h, wave_shr:1)  (R17).
//  - output conveyor fused: ov = dpp(old=h, src=ov, wave_shl:1) (R18).
//  - ramp loop g=0..8 (freeze), steady loop g=9..24 (freeze-free) (R18).
//  - seam ring: per-GROUP conveyor dump; reads barrier-covered, races
//    disjoint-or-identical, overwrite >=2 barriers away (R16 proof).
//  - out: coalesced 64-lane stores at s=206,270,334,398 (k==14, g=12,16,20,24).
__global__ __launch_bounds__(128, 1) void gru_stack_wavefront(
    const float* __restrict__ x,
    const float* __restrict__ w_ih,
    const float* __restrict__ w_hh,
    const float* __restrict__ b_ih,
    const float* __restrict__ b_hh,
    float* __restrict__ out)
{
    __shared__ float ring[2 * 64];        // [wid][slot]: h(63) / h(127) history
    __shared__ float sx[T_LEN];
    const int tid  = threadIdx.x;         // 0..127 == layer index
    const int lane = tid & 63;
    const int wid  = tid >> 6;

    ring[tid] = 0.0f;                     // zero-init both planes
    sx[tid] = x[tid];
    sx[tid + 128] = x[tid + 128];

    const float L1 = -1.4426950408889634f;   // -log2(e)
    const float L2 = -2.8853900817779268f;   // -2*log2(e)

    const float wi_r = L1 * w_ih[3 * tid + 0], wh_r = L1 * w_hh[3 * tid + 0];
    const float b_r  = L1 * (b_ih[3 * tid + 0] + b_hh[3 * tid + 0]);
    const float wi_z = L1 * w_ih[3 * tid + 1], wh_z = L1 * w_hh[3 * tid + 1];
    const float b_z  = L1 * (b_ih[3 * tid + 1] + b_hh[3 * tid + 1]);
    const float wi_n = L2 * w_ih[3 * tid + 2], bi_n = L2 * b_ih[3 * tid + 2];
    const float wh_n = L2 * w_hh[3 * tid + 2], bh_n = L2 * b_hh[3 * tid + 2];

    float h = 0.0f;
    float c_r = b_r, c_z = b_z, g_n = bh_n;

    float pk[16];
    #pragma unroll
    for (int k = 0; k < 16; ++k) pk[k] = 0.0f;

    float ov = 0.0f;                      // conveyor: w0 feeds seam dump, w1 out
    int t = -lane - 80 * wid - 1;         // ++ at step top (ramp loop only)

    const bool is_w1 = (wid == 1);
    float* ringw = &ring[wid * 64];       // own plane (w1's never read)

    __syncthreads();                      // ring + sx init visible

    // ---------- ramp loop: g = 0..8 (s = 0..143), freeze active ----------
    for (int g = 0; g < 9; ++g) {
        if (is_w1) {
            const int base = 16 * g - 17;
            #pragma unroll
            for (int k = 0; k < 16; ++k)
                pk[k] = ring[(base + k) & 63];           // h(63, s-17)
        } else {
            #pragma unroll
            for (int k = 0; k < 16; ++k)
                pk[k] = sx[16 * g + k];                  // x[s], s <= 143
        }

        #pragma unroll
        for (int k = 0; k < 16; ++k) {
            ++t;
            const bool valid = (unsigned)t < (unsigned)T_LEN;

            float in = dpp_shr1_fill(pk[k], h);          // one-instr input path

            float u_r  = fmaf(wi_r, in, c_r);
            float u_z  = fmaf(wi_z, in, c_z);
            float u_n0 = fmaf(wi_n, in, bi_n);
            float r  = rcpf_(1.0f + ex2(u_r));
            float Ez = ex2(u_z);
            Ez = valid ? Ez : 0.0f;                      // freeze: h' = h (exact at h=0)
            float En = ex2(fmaf(r, g_n, u_n0));
            float t1  = 1.0f + En;                       // (1+E_n)
            float den = fmaf(Ez, t1, t1);                // (1+E_n)(1+E_z)
            float bb  = fmaf(-Ez, En, Ez);               // E_z(1-E_n), off-chain
            float num = fmaf(h, t1, bb);                 // h(1+E_n) + E_z(1-E_n)
            h = num * rcpf_(den);

            c_r = fmaf(wh_r, h, b_r);
            c_z = fmaf(wh_z, h, b_z);
            g_n = fmaf(wh_n, h, bh_n);

            ov = dpp_shl1_fill(h, ov);                   // fused rotate+inject
        }
        ringw[(16 * g + 16 + lane) & 63] = ov;           // group-end dump
        __syncthreads();
    }

    // ---------- steady loop: g = 9..24, freeze-free (ramp-out garbage
    // provably never consumed; NaN contained — see header) ----------
    for (int g = 9; g < NG; ++g) {
        if (is_w1) {
            const int base = 16 * g - 17;
            #pragma unroll
            for (int k = 0; k < 16; ++k)
                pk[k] = ring[(base + k) & 63];           // h(63, s-17)
        } else {
            #pragma unroll
            for (int k = 0; k < 16; ++k)
                pk[k] = sx[(16 * g + k) & (T_LEN - 1)];  // x[s] (wrap: dead lanes)
        }

        #pragma unroll
        for (int k = 0; k < 16; ++k) {
            float in = dpp_shr1_fill(pk[k], h);          // one-instr input path

            float u_r  = fmaf(wi_r, in, c_r);
            float u_z  = fmaf(wi_z, in, c_z);
            float u_n0 = fmaf(wi_n, in, bi_n);
            float r  = rcpf_(1.0f + ex2(u_r));
            float Ez = ex2(u_z);
            float En = ex2(fmaf(r, g_n, u_n0));
            float t1  = 1.0f + En;
            float den = fmaf(Ez, t1, t1);
            float bb  = fmaf(-Ez, En, Ez);
            float num = fmaf(h, t1, bb);
            h = num * rcpf_(den);

            c_r = fmaf(wh_r, h, b_r);
            c_z = fmaf(wh_z, h, b_z);
            g_n = fmaf(wh_n, h, bh_n);

            ov = dpp_shl1_fill(h, ov);                   // fused rotate+inject

            if (k == 14) {                               // s = 206,270,334,398
                if (is_w1 && (g & 3) == 0 && g >= 12)
                    out[16 * g - 192 + lane] = ov;       // coalesced store
            }
        }
        ringw[(16 * g + 16 + lane) & 63] = ov;           // group-end dump
        __syncthreads();
    }
}

extern "C" void kernel_launch(void* const* d_in, const int* in_sizes, int n_in,
                              void* d_out, int out_size, void* d_ws, size_t ws_size,
                              hipStream_t stream) {
    const float* x    = (const float*)d_in[0];  // [1,256]
    const float* w_ih = (const float*)d_in[1];  // [128,3,1]
    const float* w_hh = (const float*)d_in[2];  // [128,3,1]
    const float* b_ih = (const float*)d_in[3];  // [128,3]
    const float* b_hh = (const float*)d_in[4];  // [128,3]
    float* out = (float*)d_out;                 // [1,256]

    gru_stack_wavefront<<<1, 128, 0, stream>>>(x, w_ih, w_hh, b_ih, b_hh, out);
}